// Round 5
// baseline (107.892 us; speedup 1.0000x reference)
//
#include <hip/hip_runtime.h>
#include <math.h>

#define NF 512         // feature count
#define NP 118         // raw params per feature
#define NPPAD 126      // padded: L0 at 0 (+1 pad), middle li at 10+16*(li-1), final at 122
#define FT 16          // features per block tile
#define ROWS 8         // rows per thread (4 row-pairs)
#define BLOCK_ROWS 128 // (256/FT) rowgroups * ROWS
#define WS_NEED ((size_t)(NPPAD * NF) * sizeof(float))

typedef float v2f __attribute__((ext_vector_type(2)));

// ---- explicit VOP3P packed fp32 FMA with op_sel broadcasts ----
// f_XY: src1 uses half X, src2 uses half Y; P = normal pair.
__device__ __forceinline__ v2f f_PP(v2f a, v2f b, v2f c) {
    v2f d; asm("v_pk_fma_f32 %0, %1, %2, %3" : "=v"(d) : "v"(a), "v"(b), "v"(c)); return d;
}
__device__ __forceinline__ v2f f_LP(v2f a, v2f b, v2f c) {  // b broadcast lo
    v2f d; asm("v_pk_fma_f32 %0, %1, %2, %3 op_sel_hi:[1,0,1]" : "=v"(d) : "v"(a), "v"(b), "v"(c)); return d;
}
__device__ __forceinline__ v2f f_HP(v2f a, v2f b, v2f c) {  // b broadcast hi
    v2f d; asm("v_pk_fma_f32 %0, %1, %2, %3 op_sel:[0,1,0] op_sel_hi:[1,1,1]" : "=v"(d) : "v"(a), "v"(b), "v"(c)); return d;
}
__device__ __forceinline__ v2f f_LH(v2f a, v2f b, v2f c) {  // b lo, c hi
    v2f d; asm("v_pk_fma_f32 %0, %1, %2, %3 op_sel:[0,0,1] op_sel_hi:[1,0,1]" : "=v"(d) : "v"(a), "v"(b), "v"(c)); return d;
}
__device__ __forceinline__ v2f f_HL(v2f a, v2f b, v2f c) {  // b hi, c lo
    v2f d; asm("v_pk_fma_f32 %0, %1, %2, %3 op_sel:[0,1,0] op_sel_hi:[1,1,0]" : "=v"(d) : "v"(a), "v"(b), "v"(c)); return d;
}

__device__ __forceinline__ float fast_rcp(float x) { return __builtin_amdgcn_rcpf(x); }

__device__ __forceinline__ float exp2_fast(float x) {
#if __has_builtin(__builtin_amdgcn_exp2f)
    return __builtin_amdgcn_exp2f(x);
#else
    return __expf(x * 0.6931471805599453f);
#endif
}

// tanh(x) = 1 - 2/(2^(2*log2e*x) + 1): 3 VALU + 2 trans per scalar, no LDS.
__device__ __forceinline__ float tanh1(float x) {
    float e = exp2_fast(x * 2.8853900817779268f);
    return fmaf(-2.0f, fast_rcp(e + 1.0f), 1.0f);
}
__device__ __forceinline__ v2f tanh_pair(v2f a) {
    v2f t;
    t.x = tanh1(a.x);
    t.y = tanh1(a.y);
    return t;
}
__device__ __forceinline__ float sigmoid1(float x) {
    return fast_rcp(1.0f + exp2_fast(x * -1.4426950408889634f));
}

// ---- parameter transform ----
__device__ __forceinline__ float transform_one(float v, int j) {
    int cls;
    if (j < 3) cls = 0;
    else if (j < 6) cls = 1;
    else if (j < 9) cls = 2;
    else if (j < 114) { int k = (j - 9) % 15; cls = (k < 9) ? 0 : ((k < 12) ? 1 : 2); }
    else if (j < 117) cls = 0;
    else cls = 1;
    if (cls == 0) return fmaxf(v, 0.0f) + log1pf(expf(-fabsf(v)));  // stable softplus
    if (cls == 2) return tanhf(v);
    return v;
}

__device__ __forceinline__ bool map_padded(int jp, int* j) {
    if (jp < 9) { *j = jp; return true; }
    if (jp == 9) return false;
    if (jp < 122) {
        int k = (jp - 10) & 15, li = (jp - 10) >> 4;
        if (k == 15) return false;
        *j = 9 + 15 * li + k;
        return true;
    }
    *j = 114 + (jp - 122);
    return true;
}

__device__ __forceinline__ float transform_padded(const float* __restrict__ prow, int jp) {
    int j;
    if (!map_padded(jp, &j)) return 0.0f;
    return transform_one(prow[j], j);
}

// Kernel 1: padded+transformed params transposed t[jp*NF+f].
__global__ void xform_kernel(const float* __restrict__ p, float* __restrict__ t) {
    int idx = blockIdx.x * 256 + threadIdx.x;
    if (idx < NPPAD * NF) {
        int jp = idx / NF, f = idx - jp * NF;
        t[idx] = transform_padded(p + f * NP, jp);
    }
}

template <bool FUSE_XFORM>
__global__ __launch_bounds__(256, 8)
void cdf_kernel(const float* __restrict__ x, const float* __restrict__ prm,
                float* __restrict__ out) {
    __shared__ float ldsp[NPPAD * FT];   // pair-interleaved: [(jp>>1)][fi][2]
    const int tid = threadIdx.x;
    const int fi  = tid & (FT - 1);
    const int rg  = tid >> 4;            // 16 rowgroups
    const int f0  = blockIdx.x * FT;
    const int b0  = blockIdx.y * BLOCK_ROWS + rg * ROWS;
    const int f   = f0 + fi;

    if constexpr (FUSE_XFORM) {
        for (int idx = tid; idx < NPPAD * FT; idx += 256) {
            int jp = idx >> 4, fl = idx & (FT - 1);
            ldsp[(jp >> 1) * (2 * FT) + fl * 2 + (jp & 1)] =
                transform_padded(prm + (f0 + fl) * NP, jp);
        }
    } else {
        for (int idx = tid; idx < NPPAD * FT; idx += 256) {
            int jp = idx >> 4, fl = idx & (FT - 1);
            ldsp[(jp >> 1) * (2 * FT) + fl * 2 + (jp & 1)] = prm[jp * NF + f0 + fl];
        }
    }

    v2f xin[4];
#pragma unroll
    for (int r = 0; r < 4; ++r) {
        xin[r].x = x[(b0 + 2 * r)     * NF + f];
        xin[r].y = x[(b0 + 2 * r + 1) * NF + f];
    }

    __syncthreads();

    const float* Pp = ldsp + fi * 2;
#define PRMV(JP) (*reinterpret_cast<const v2f*>(Pp + (JP) * FT))

    v2f h0[4], h1[4], h2[4];
    // ---- layer 0: pairs {w0,w1},{w2,c0},{c1,c2},{s0,s1},{s2,pad} ----
    {
        v2f q0 = PRMV(0), q1 = PRMV(2), q2 = PRMV(4), q3 = PRMV(6), q4 = PRMV(8);
#pragma unroll
        for (int r = 0; r < 4; ++r) {
            v2f a0 = f_LH(xin[r], q0, q1);   // w0*x + c0
            v2f a1 = f_HL(xin[r], q0, q2);   // w1*x + c1
            v2f a2 = f_LH(xin[r], q1, q2);   // w2*x + c2
            v2f T0 = tanh_pair(a0);
            v2f T1 = tanh_pair(a1);
            v2f T2 = tanh_pair(a2);
            h0[r] = f_LP(T0, q3, a0);        // a0 + s0*T0
            h1[r] = f_HP(T1, q3, a1);        // a1 + s1*T1
            h2[r] = f_LP(T2, q4, a2);        // a2 + s2*T2
        }
    }
    // ---- middle layers 1..7: pairs {w00,w01},{w02,w10},{w11,w12},{w20,w21},
    //                                 {w22,c0},{c1,c2},{s0,s1},{s2,pad} ----
#pragma unroll
    for (int li = 1; li < 8; ++li) {
        const int bp = 10 + 16 * (li - 1);
        v2f q0 = PRMV(bp + 0), q1 = PRMV(bp + 2), q2 = PRMV(bp + 4), q3 = PRMV(bp + 6);
        v2f q4 = PRMV(bp + 8), q5 = PRMV(bp + 10), q6 = PRMV(bp + 12), q7 = PRMV(bp + 14);
#pragma unroll
        for (int r = 0; r < 4; ++r) {
            v2f t0 = f_LH(h0[r], q0, q4);    // w00*h0 + c0
            t0     = f_HP(h1[r], q0, t0);    // + w01*h1
            v2f a0 = f_LP(h2[r], q1, t0);    // + w02*h2
            v2f t1 = f_HL(h0[r], q1, q5);    // w10*h0 + c1
            t1     = f_LP(h1[r], q2, t1);    // + w11*h1
            v2f a1 = f_HP(h2[r], q2, t1);    // + w12*h2
            v2f t2 = f_LH(h0[r], q3, q5);    // w20*h0 + c2
            t2     = f_HP(h1[r], q3, t2);    // + w21*h1
            v2f a2 = f_LP(h2[r], q4, t2);    // + w22*h2
            v2f T0 = tanh_pair(a0);
            v2f T1 = tanh_pair(a1);
            v2f T2 = tanh_pair(a2);
            h0[r] = f_LP(T0, q6, a0);
            h1[r] = f_HP(T1, q6, a1);
            h2[r] = f_LP(T2, q7, a2);
        }
    }
    // ---- final layer: a = w.h + b, out = sigmoid(a) ----
    {
        v2f q8 = PRMV(122), q9 = PRMV(124);  // {w0,w1},{w2,cb}
#pragma unroll
        for (int r = 0; r < 4; ++r) {
            v2f a = f_LH(h0[r], q8, q9);
            a     = f_HP(h1[r], q8, a);
            a     = f_LP(h2[r], q9, a);
            out[(b0 + 2 * r)     * NF + f] = sigmoid1(a.x);
            out[(b0 + 2 * r + 1) * NF + f] = sigmoid1(a.y);
        }
    }
#undef PRMV
}

extern "C" void kernel_launch(void* const* d_in, const int* in_sizes, int n_in,
                              void* d_out, int out_size, void* d_ws, size_t ws_size,
                              hipStream_t stream) {
    const float* x = (const float*)d_in[0];       // (B, 512) f32
    const float* p = (const float*)d_in[1];       // (512, 118) f32
    float* out = (float*)d_out;                   // (B, 512) f32

    const int B = in_sizes[0] / NF;               // 32768
    dim3 grid(NF / FT, B / BLOCK_ROWS);           // (32, 256)
    dim3 block(256);

    if (ws_size >= WS_NEED) {
        float* t = (float*)d_ws;
        xform_kernel<<<(NPPAD * NF + 255) / 256, 256, 0, stream>>>(p, t);
        cdf_kernel<false><<<grid, block, 0, stream>>>(x, t, out);
    } else {
        cdf_kernel<true><<<grid, block, 0, stream>>>(x, p, out);
    }
}